// Round 8
// baseline (169.176 us; speedup 1.0000x reference)
//
#include <hip/hip_runtime.h>
#include <hip/hip_fp16.h>

// GCNConv (PyG semantics) + eval-dropout(identity) + ReLU, fp32 in/out.
// N=100000 nodes, E=1600000 edges, D=64.
//
// Round-7 post-mortem: gather occupancy 46% (391x1024thr, 1.53 blk/CU
// quantization), k_part 1 blk/CU (38KB LDS) + 9-step binary search,
// k_gemm 1.53 blk/CU with serial hist->MFMA phases. This round:
//  1. k_part: EPB 4096 -> 391 blocks ALL resident (2/CU, ~30KB LDS);
//     srtb[] u16 bucket-per-slot kills the binary search (2 LDS reads).
//     Block 0: bf16 WT + zero dummy row N of xw_h.
//  2. k_gemm: 782 HALF-bucket blocks (128 rows = 8 M-tiles, 4 waves x 2)
//     -> 3 blk/CU; hist filtered to own half (bit7); x-loads hoisted into
//     regs BEFORE hist (HBM latency hides under hist). MFMA 16x16x32_bf16
//     swapped-operand (transposed-C -> 8B stores), B-frags from WT.
//  3. k_gather: 782 half-bucket blocks x 512 thr (~20KB LDS -> 3 blk/CU);
//     engine: l=lane&7 (uint4 = 16B dim-chunk), q=lane>>3 (8 edge slots),
//     x16-padded segments (dummy row N = zeros), 2 loads/lane/round,
//     2-stage pipeline (64B/lane in flight), shfl-xor(8,16,32) reduce,
//     fused bias+ReLU, nontemporal stores.
//
// Workspace ~20.5 MB (< proven-safe 22.8 MB).

#define D 64
#define BW 256             // dest nodes per bucket (partition granularity)
#define CAPB 4800          // dense per-bucket capacity (mean 4092, +11 sigma)
#define CAPL2 4608         // srtL capacity per HALF bucket (mean 2048 + x16 pad)
#define EPT 8              // edges per thread in k_part
#define PART_T 512
#define EPB (PART_T * EPT) // 4096 edges per partition block
#define NBMAX 512
#define GSTRIDE 16         // gcur stride (64B) to spread atomic lines

typedef __attribute__((ext_vector_type(8))) short bf16x8;
typedef __attribute__((ext_vector_type(4))) float f32x4;

__device__ __forceinline__ unsigned short f2bf(float f) {   // RNE fp32->bf16
    unsigned u = __float_as_uint(f);
    u += 0x7FFFu + ((u >> 16) & 1u);
    return (unsigned short)(u >> 16);
}

// ---- 1. partition: hist -> atomic bases -> LDS sort -> dense writes --------
__global__ __launch_bounds__(512, 4)
void k_part(const int* __restrict__ row, const int* __restrict__ col,
            int* __restrict__ gcur, int* __restrict__ dense,
            unsigned short* __restrict__ WT, const float* __restrict__ W,
            unsigned short* __restrict__ xw_h,
            int E, int NBUCK, int N) {
    __shared__ int lh[NBMAX];
    __shared__ int lst[NBMAX + 1];
    __shared__ int bas[NBMAX];
    __shared__ int wsc[8];
    __shared__ int srtv[EPB];
    __shared__ unsigned short srtb[EPB];
    int tid = threadIdx.x;
    for (int i = tid; i < NBUCK; i += PART_T) lh[i] = 0;
    __syncthreads();
    int e0 = blockIdx.x * EPB + tid;
    int rr[EPT], cc[EPT], pp[EPT];
#pragma unroll
    for (int i = 0; i < EPT; ++i) {
        int e = e0 + i * PART_T;
        if (e < E) {
            cc[i] = __builtin_nontemporal_load(col + e);
            rr[i] = __builtin_nontemporal_load(row + e);
            pp[i] = atomicAdd(&lh[cc[i] >> 8], 1);   // LDS rank in bucket
        } else {
            cc[i] = -1;
        }
    }
    __syncthreads();
    // per-(block,bucket) global base via atomic (rotated to spread lines)
    int rot = (int)((blockIdx.x * 97u) % (unsigned)NBUCK);
    for (int j = tid; j < NBUCK; j += PART_T) {
        int bu = j + rot; if (bu >= NBUCK) bu -= NBUCK;
        int h = lh[bu];
        if (h > 0) bas[bu] = atomicAdd(&gcur[bu * GSTRIDE], h);
    }
    // exclusive scan over NBUCK counts (NBUCK <= 512, 1 entry/thread)
    int lane = tid & 63, wv = tid >> 6;
    int v = (tid < NBUCK) ? lh[tid] : 0;
    int inc = v;
#pragma unroll
    for (int o = 1; o < 64; o <<= 1) {
        int u = __shfl_up(inc, o);
        if (lane >= o) inc += u;
    }
    if (lane == 63) wsc[wv] = inc;
    __syncthreads();
    int woff = 0;
#pragma unroll
    for (int w = 0; w < 8; ++w) woff += (w < wv) ? wsc[w] : 0;
    if (tid < NBUCK) lst[tid] = woff + inc - v;
    int tot = min(EPB, E - blockIdx.x * EPB);
    if (tid == 0) lst[NBUCK] = tot;
    __syncthreads();
    // scatter into LDS sorted by bucket (+ record bucket per slot)
#pragma unroll
    for (int i = 0; i < EPT; ++i) {
        if (cc[i] >= 0) {
            int bu = cc[i] >> 8;
            int pos = lst[bu] + pp[i];
            srtv[pos] = (rr[i] << 8) | (cc[i] & 255);
            srtb[pos] = (unsigned short)bu;
        }
    }
    __syncthreads();
    // coalesced run writes to bucket-major dense (no binary search)
    for (int p = tid; p < tot; p += PART_T) {
        int bu = srtb[p];
        int gpos = bas[bu] + (p - lst[bu]);
        if (gpos < CAPB) dense[(size_t)bu * CAPB + gpos] = srtv[p];
    }
    // block 0 extras: transposed bf16 W, zero dummy row N
    if (blockIdx.x == 0) {
        for (int i = tid; i < 4096; i += PART_T) {
            int n = i >> 6, k = i & 63;
            WT[i] = f2bf(W[k * 64 + n]);           // WT[n][k]
        }
        if (tid < 32) ((unsigned*)xw_h)[(size_t)N * 32 + tid] = 0u;
    }
}

// ---- 2. MFMA GEMM (transposed-C), half-bucket blocks, hoisted x loads ------
// Block b2: bucket b2>>1, half b2&1 -> 128 rows = 8 M-tiles (4 waves x 2).
// mfma(A=WT-frag, B=x-frag): thread (m,quad) holds row row0+m, cols
// t*16+quad*4.. -> 8B stores.
__global__ __launch_bounds__(256, 4)
void k_gemm(const float* __restrict__ x, const unsigned short* __restrict__ WT,
            const int* __restrict__ dense, const int* __restrict__ gcur,
            unsigned char* __restrict__ deg8, unsigned short* __restrict__ xw_h,
            int N, int NT) {
    __shared__ int lh[128];
    int tid = threadIdx.x, b2 = blockIdx.x;
    int bucket = b2 >> 1, hf = b2 & 1;
    int lane = tid & 63, wv = tid >> 6;
    int m = lane & 15, quad = lane >> 4;
    // hoist x loads (HBM latency hides under histogram below)
    f32x4 xa[2][4];
#pragma unroll
    for (int s = 0; s < 2; ++s) {
        int mt = b2 * 8 + s * 4 + wv;
        if (mt < NT) {
            const float* xr = x + (size_t)(mt * 16 + m) * 64 + quad * 8;
            xa[s][0] = __builtin_nontemporal_load((const f32x4*)(xr));
            xa[s][1] = __builtin_nontemporal_load((const f32x4*)(xr + 4));
            xa[s][2] = __builtin_nontemporal_load((const f32x4*)(xr + 32));
            xa[s][3] = __builtin_nontemporal_load((const f32x4*)(xr + 36));
        }
    }
    if (tid < 128) lh[tid] = 0;
    __syncthreads();
    int tot = min(gcur[bucket * GSTRIDE], CAPB);
    const int* dn = dense + (size_t)bucket * CAPB;
    int hsel = hf << 7;
    for (int i = tid; i < tot; i += 256) {
        int val = __builtin_nontemporal_load(dn + i);
        if ((val & 128) == hsel) atomicAdd(&lh[val & 127], 1);
    }
    __syncthreads();
    if (tid < 128) {
        int node = b2 * 128 + tid;
        if (node < N) deg8[node] = (unsigned char)min(lh[tid], 255);
    }
    bf16x8 Bf[4][2];
#pragma unroll
    for (int t = 0; t < 4; ++t)
#pragma unroll
        for (int s = 0; s < 2; ++s)
            Bf[t][s] = *(const bf16x8*)(WT + (t * 16 + m) * 64 + s * 32 + quad * 8);
#pragma unroll
    for (int s = 0; s < 2; ++s) {
        int mt = b2 * 8 + s * 4 + wv;
        if (mt >= NT) continue;
        int row0 = mt * 16;
        bf16x8 A0, A1;
        A0[0] = (short)f2bf(xa[s][0][0]); A0[1] = (short)f2bf(xa[s][0][1]);
        A0[2] = (short)f2bf(xa[s][0][2]); A0[3] = (short)f2bf(xa[s][0][3]);
        A0[4] = (short)f2bf(xa[s][1][0]); A0[5] = (short)f2bf(xa[s][1][1]);
        A0[6] = (short)f2bf(xa[s][1][2]); A0[7] = (short)f2bf(xa[s][1][3]);
        A1[0] = (short)f2bf(xa[s][2][0]); A1[1] = (short)f2bf(xa[s][2][1]);
        A1[2] = (short)f2bf(xa[s][2][2]); A1[3] = (short)f2bf(xa[s][2][3]);
        A1[4] = (short)f2bf(xa[s][3][0]); A1[5] = (short)f2bf(xa[s][3][1]);
        A1[6] = (short)f2bf(xa[s][3][2]); A1[7] = (short)f2bf(xa[s][3][3]);
        f32x4 acc[4];
#pragma unroll
        for (int t = 0; t < 4; ++t) {
            acc[t] = (f32x4){0.f, 0.f, 0.f, 0.f};
            acc[t] = __builtin_amdgcn_mfma_f32_16x16x32_bf16(Bf[t][0], A0, acc[t], 0, 0, 0);
            acc[t] = __builtin_amdgcn_mfma_f32_16x16x32_bf16(Bf[t][1], A1, acc[t], 0, 0, 0);
        }
        float dsc = rsqrtf((float)(lh[(row0 + m) & 127] + 1));
        unsigned short* op = xw_h + (size_t)(row0 + m) * 64 + quad * 4;
#pragma unroll
        for (int t = 0; t < 4; ++t) {
            __half2 h0, h1;
            h0.x = __float2half(acc[t][0] * dsc); h0.y = __float2half(acc[t][1] * dsc);
            h1.x = __float2half(acc[t][2] * dsc); h1.y = __float2half(acc[t][3] * dsc);
            uint2 u; u.x = *(unsigned*)&h0; u.y = *(unsigned*)&h1;
            *(uint2*)(op + t * 16) = u;
        }
    }
}

// ---- 3. uniform-node gather, half-bucket blocks, uint4 engine --------------
__global__ __launch_bounds__(512, 6)
void k_gather(const int* __restrict__ dense, const int* __restrict__ gcur,
              const unsigned char* __restrict__ deg8,
              const uint4* __restrict__ xwh4, const float* __restrict__ bias,
              float* __restrict__ out, int N) {
    __shared__ int lh[128], stt[128], cur[128];
    __shared__ int wsum[2];
    __shared__ __align__(16) int srtL[CAPL2];
    int b2 = blockIdx.x, tid = threadIdx.x, lane = tid & 63;
    int bucket = b2 >> 1, hf = b2 & 1;
    int nb0 = b2 * 128;
    // per-node counts from deg8, padded-x16 exclusive scan (waves 0-1)
    int v = 0, vp = 0, inc = 0;
    if (tid < 128) {
        int node = nb0 + tid;
        v = (node < N) ? (int)deg8[node] : 0;
        lh[tid] = v;
        vp = (v + 15) & ~15; inc = vp;
#pragma unroll
        for (int o = 1; o < 64; o <<= 1) {
            int u = __shfl_up(inc, o);
            if (lane >= o) inc += u;
        }
        if (lane == 63) wsum[tid >> 6] = inc;
    }
    __syncthreads();
    if (tid < 128) {
        int st = inc - vp + ((tid >> 6) ? wsum[0] : 0);
        stt[tid] = st;
        cur[tid] = st;
    }
    __syncthreads();
    // rank-scatter this half's edges from contiguous dense
    int tot = min(gcur[bucket * GSTRIDE], CAPB);
    const int* dn = dense + (size_t)bucket * CAPB;
    int hsel = hf << 7;
    for (int i = tid; i < tot; i += 512) {
        int val = __builtin_nontemporal_load(dn + i);
        if ((val & 128) == hsel) {
            int pos = atomicAdd(&cur[val & 127], 1);
            if (pos < CAPL2) srtL[pos] = val >> 8;
        }
    }
    __syncthreads();
    if (tid < 128) {           // pad each segment to x16 with dummy row N
        int e = stt[tid] + v, ep = min(stt[tid] + vp, CAPL2);
        for (; e < ep; ++e) srtL[e] = N;
    }
    __syncthreads();
    int q = lane >> 3;         // edge slot 0..7
    int l = lane & 7;          // dim chunk: halves 8l..8l+7 (uint4)
    int wv = tid >> 6;         // 8 waves, 16 nodes each
    const float4 b0 = ((const float4*)bias)[2 * l];
    const float4 b1 = ((const float4*)bias)[2 * l + 1];
#define ADDV16(u)                                                     \
    {                                                                 \
        __half2 p0 = *(__half2*)&(u).x, p1 = *(__half2*)&(u).y;       \
        __half2 p2 = *(__half2*)&(u).z, p3 = *(__half2*)&(u).w;       \
        float2 f0 = __half22float2(p0), f1 = __half22float2(p1);      \
        float2 f2 = __half22float2(p2), f3 = __half22float2(p3);      \
        accA.x += f0.x; accA.y += f0.y; accA.z += f1.x; accA.w += f1.y;\
        accB.x += f2.x; accB.y += f2.y; accB.z += f3.x; accB.w += f3.y;\
    }
    for (int nn = wv * 16; nn < wv * 16 + 16; ++nn) {
        int node = nb0 + nn;
        if (node >= N) break;
        int k = lh[nn], s0 = stt[nn];
        int kp = (k + 15) & ~15;
        if (s0 + kp > CAPL2) kp = (CAPL2 > s0) ? ((CAPL2 - s0) & ~15) : 0;
        float4 accA = make_float4(0.f, 0.f, 0.f, 0.f);
        float4 accB = make_float4(0.f, 0.f, 0.f, 0.f);
        if (q == 0) { uint4 hs = xwh4[(size_t)node * 8 + l]; ADDV16(hs); } // self
        int rounds = kp >> 4;
        if (rounds > 0) {      // 2-stage pipeline: 4 uint4 loads in flight
            int i0 = s0 + q;
            int r0 = srtL[i0], r1 = srtL[i0 + 8];
            uint4 va = xwh4[(size_t)r0 * 8 + l];
            uint4 vb = xwh4[(size_t)r1 * 8 + l];
            for (int r = 1; r < rounds; ++r) {
                i0 += 16;
                int n0 = srtL[i0], n1 = srtL[i0 + 8];
                uint4 wa = xwh4[(size_t)n0 * 8 + l];
                uint4 wb = xwh4[(size_t)n1 * 8 + l];
                ADDV16(va); ADDV16(vb);
                va = wa; vb = wb;
            }
            ADDV16(va); ADDV16(vb);
        }
        // reduce across the 8 edge slots (q): xor 8, 16, 32
#pragma unroll
        for (int mm = 8; mm < 64; mm <<= 1) {
            accA.x += __shfl_xor(accA.x, mm); accA.y += __shfl_xor(accA.y, mm);
            accA.z += __shfl_xor(accA.z, mm); accA.w += __shfl_xor(accA.w, mm);
            accB.x += __shfl_xor(accB.x, mm); accB.y += __shfl_xor(accB.y, mm);
            accB.z += __shfl_xor(accB.z, mm); accB.w += __shfl_xor(accB.w, mm);
        }
        if (q == 0) {
            float dn2 = rsqrtf((float)(k + 1));
            f32x4 o1, o2;
            o1[0] = fmaxf(fmaf(dn2, accA.x, b0.x), 0.f);
            o1[1] = fmaxf(fmaf(dn2, accA.y, b0.y), 0.f);
            o1[2] = fmaxf(fmaf(dn2, accA.z, b0.z), 0.f);
            o1[3] = fmaxf(fmaf(dn2, accA.w, b0.w), 0.f);
            o2[0] = fmaxf(fmaf(dn2, accB.x, b1.x), 0.f);
            o2[1] = fmaxf(fmaf(dn2, accB.y, b1.y), 0.f);
            o2[2] = fmaxf(fmaf(dn2, accB.z, b1.z), 0.f);
            o2[3] = fmaxf(fmaf(dn2, accB.w, b1.w), 0.f);
            float* op = out + (size_t)node * 64 + l * 8;
            __builtin_nontemporal_store(o1, (f32x4*)op);
            __builtin_nontemporal_store(o2, (f32x4*)(op + 4));
        }
    }
#undef ADDV16
}

extern "C" void kernel_launch(void* const* d_in, const int* in_sizes, int n_in,
                              void* d_out, int out_size, void* d_ws, size_t ws_size,
                              hipStream_t stream) {
    const float* x    = (const float*)d_in[0];
    const int*   ei   = (const int*)d_in[1];   // int32 (JAX demotes int64)
    const float* W    = (const float*)d_in[2];
    const float* bias = (const float*)d_in[3];
    float* out = (float*)d_out;

    const int N = in_sizes[0] / D;
    const int E = in_sizes[1] / 2;
    const int* row = ei;       // edge_index[0] = sources
    const int* col = ei + E;   // edge_index[1] = destinations

    const int NBUCK = (N + BW - 1) / BW;       // 391
    const int NB1   = (E + EPB - 1) / EPB;     // 391
    const int NT    = (N + 15) / 16;           // 6250 M-tiles
    const int NH    = 2 * NBUCK;               // 782 half-buckets

    char* ws = (char*)d_ws;
    size_t o = 0;
    unsigned short* xw_h = (unsigned short*)(ws + o);
    o += (size_t)(N + 1) * D * sizeof(unsigned short);             // 12.8 MB
    int* dense = (int*)(ws + o); o += (size_t)NBUCK * CAPB * sizeof(int); // 7.5 MB
    int* gcur  = (int*)(ws + o); o += (size_t)NBUCK * GSTRIDE * sizeof(int); // 25 KB
    unsigned char* deg8 = (unsigned char*)(ws + o); o += (size_t)N;
    o = (o + 15) & ~(size_t)15;
    unsigned short* WT = (unsigned short*)(ws + o); o += 4096 * sizeof(unsigned short);

    hipMemsetAsync(gcur, 0, (size_t)NBUCK * GSTRIDE * sizeof(int), stream);
    k_part<<<NB1, PART_T, 0, stream>>>(row, col, gcur, dense, WT, W, xw_h, E, NBUCK, N);
    k_gemm<<<NH, 256, 0, stream>>>(x, WT, dense, gcur, deg8, xw_h, N, NT);
    k_gather<<<NH, 512, 0, stream>>>(dense, gcur, deg8, (const uint4*)xw_h,
                                     bias, out, N);
}

// Round 9
// 167.775 us; speedup vs baseline: 1.0084x; 1.0084x over previous
//
#include <hip/hip_runtime.h>
#include <hip/hip_fp16.h>

// GCNConv (PyG semantics) + eval-dropout(identity) + ReLU, fp32 in/out.
// N=100000 nodes, E=1600000 edges, D=64.
//
// Round-8 post-mortem: half-bucket gather doubled per-block overhead (2x
// dense read + 2x scatter iters) -> 45.4->56.6us regression, while k_part
// (srtb, EPB4096) and k_gemm (half-blocks, hoisted x) improved (~8us).
// This round: keep r8 part/gemm; gather = full-bucket 391x1024thr (r7's
// best config) + uint4 engine (16B/lane, 8 slots, half the load instrs)
// + single unfiltered dense read + parallel x16 pad.
//
//  1. k_part: LDS hist -> atomic per-(block,bucket) bases -> LDS sort
//     (srtb bucket-per-slot, no binary search) -> bucket-major dense
//     writes. Block 0: bf16 WT + zero dummy row N of xw_h.
//  2. k_gemm: 782 half-bucket blocks (128 rows, 4 waves x 2 tiles); x
//     loads hoisted before the filtered hist (latency overlap); MFMA
//     16x16x32_bf16 swapped-operand (transposed-C -> 8B stores).
//  3. k_gather: 391 blocks x 1024 thr (~31KB LDS, 2 blk/CU): deg8 ->
//     x16-padded scan, single rank-scatter from contiguous dense into
//     srtL (pad with dummy row N = zeros, 4 thr/node), engine:
//     q=lane>>3 edge slot, l=lane&7 uint4 dim-chunk, 2 loads/lane/round,
//     2-stage pipeline, shfl-xor(8,16,32) reduce, bias+ReLU, nt stores.
//
// Workspace ~20.5 MB (< proven-safe 22.8 MB).

#define D 64
#define BW 256             // dest nodes per bucket
#define CAPB 4800          // dense per-bucket capacity (mean 4092, +11 sigma)
#define CAPL 6912          // srtL capacity (mean 4092 + x16 pad ~2048, +~10s)
#define EPT 8              // edges per thread in k_part
#define PART_T 512
#define EPB (PART_T * EPT) // 4096 edges per partition block
#define NBMAX 512
#define GSTRIDE 16         // gcur stride (64B) to spread atomic lines

typedef __attribute__((ext_vector_type(8))) short bf16x8;
typedef __attribute__((ext_vector_type(4))) float f32x4;

__device__ __forceinline__ unsigned short f2bf(float f) {   // RNE fp32->bf16
    unsigned u = __float_as_uint(f);
    u += 0x7FFFu + ((u >> 16) & 1u);
    return (unsigned short)(u >> 16);
}

// ---- 1. partition: hist -> atomic bases -> LDS sort -> dense writes --------
__global__ __launch_bounds__(512, 4)
void k_part(const int* __restrict__ row, const int* __restrict__ col,
            int* __restrict__ gcur, int* __restrict__ dense,
            unsigned short* __restrict__ WT, const float* __restrict__ W,
            unsigned short* __restrict__ xw_h,
            int E, int NBUCK, int N) {
    __shared__ int lh[NBMAX];
    __shared__ int lst[NBMAX + 1];
    __shared__ int bas[NBMAX];
    __shared__ int wsc[8];
    __shared__ int srtv[EPB];
    __shared__ unsigned short srtb[EPB];
    int tid = threadIdx.x;
    for (int i = tid; i < NBUCK; i += PART_T) lh[i] = 0;
    __syncthreads();
    int e0 = blockIdx.x * EPB + tid;
    int rr[EPT], cc[EPT], pp[EPT];
#pragma unroll
    for (int i = 0; i < EPT; ++i) {
        int e = e0 + i * PART_T;
        if (e < E) {
            cc[i] = __builtin_nontemporal_load(col + e);
            rr[i] = __builtin_nontemporal_load(row + e);
            pp[i] = atomicAdd(&lh[cc[i] >> 8], 1);   // LDS rank in bucket
        } else {
            cc[i] = -1;
        }
    }
    __syncthreads();
    // per-(block,bucket) global base via atomic (rotated to spread lines)
    int rot = (int)((blockIdx.x * 97u) % (unsigned)NBUCK);
    for (int j = tid; j < NBUCK; j += PART_T) {
        int bu = j + rot; if (bu >= NBUCK) bu -= NBUCK;
        int h = lh[bu];
        if (h > 0) bas[bu] = atomicAdd(&gcur[bu * GSTRIDE], h);
    }
    // exclusive scan over NBUCK counts (NBUCK <= 512, 1 entry/thread)
    int lane = tid & 63, wv = tid >> 6;
    int v = (tid < NBUCK) ? lh[tid] : 0;
    int inc = v;
#pragma unroll
    for (int o = 1; o < 64; o <<= 1) {
        int u = __shfl_up(inc, o);
        if (lane >= o) inc += u;
    }
    if (lane == 63) wsc[wv] = inc;
    __syncthreads();
    int woff = 0;
#pragma unroll
    for (int w = 0; w < 8; ++w) woff += (w < wv) ? wsc[w] : 0;
    if (tid < NBUCK) lst[tid] = woff + inc - v;
    int tot = min(EPB, E - blockIdx.x * EPB);
    if (tid == 0) lst[NBUCK] = tot;
    __syncthreads();
    // scatter into LDS sorted by bucket (+ record bucket per slot)
#pragma unroll
    for (int i = 0; i < EPT; ++i) {
        if (cc[i] >= 0) {
            int bu = cc[i] >> 8;
            int pos = lst[bu] + pp[i];
            srtv[pos] = (rr[i] << 8) | (cc[i] & 255);
            srtb[pos] = (unsigned short)bu;
        }
    }
    __syncthreads();
    // coalesced run writes to bucket-major dense (no binary search)
    for (int p = tid; p < tot; p += PART_T) {
        int bu = srtb[p];
        int gpos = bas[bu] + (p - lst[bu]);
        if (gpos < CAPB) dense[(size_t)bu * CAPB + gpos] = srtv[p];
    }
    // block 0 extras: transposed bf16 W, zero dummy row N
    if (blockIdx.x == 0) {
        for (int i = tid; i < 4096; i += PART_T) {
            int n = i >> 6, k = i & 63;
            WT[i] = f2bf(W[k * 64 + n]);           // WT[n][k]
        }
        if (tid < 32) ((unsigned*)xw_h)[(size_t)N * 32 + tid] = 0u;
    }
}

// ---- 2. MFMA GEMM (transposed-C), half-bucket blocks, hoisted x loads ------
// Block b2: bucket b2>>1, half b2&1 -> 128 rows = 8 M-tiles (4 waves x 2).
// mfma(A=WT-frag, B=x-frag): thread (m,quad) holds row row0+m, cols
// t*16+quad*4.. -> 8B stores.
__global__ __launch_bounds__(256, 4)
void k_gemm(const float* __restrict__ x, const unsigned short* __restrict__ WT,
            const int* __restrict__ dense, const int* __restrict__ gcur,
            unsigned char* __restrict__ deg8, unsigned short* __restrict__ xw_h,
            int N, int NT) {
    __shared__ int lh[128];
    int tid = threadIdx.x, b2 = blockIdx.x;
    int bucket = b2 >> 1, hf = b2 & 1;
    int lane = tid & 63, wv = tid >> 6;
    int m = lane & 15, quad = lane >> 4;
    // hoist x loads (HBM latency hides under histogram below)
    f32x4 xa[2][4];
#pragma unroll
    for (int s = 0; s < 2; ++s) {
        int mt = b2 * 8 + s * 4 + wv;
        if (mt < NT) {
            const float* xr = x + (size_t)(mt * 16 + m) * 64 + quad * 8;
            xa[s][0] = __builtin_nontemporal_load((const f32x4*)(xr));
            xa[s][1] = __builtin_nontemporal_load((const f32x4*)(xr + 4));
            xa[s][2] = __builtin_nontemporal_load((const f32x4*)(xr + 32));
            xa[s][3] = __builtin_nontemporal_load((const f32x4*)(xr + 36));
        }
    }
    if (tid < 128) lh[tid] = 0;
    __syncthreads();
    int tot = min(gcur[bucket * GSTRIDE], CAPB);
    const int* dn = dense + (size_t)bucket * CAPB;
    int hsel = hf << 7;
    for (int i = tid; i < tot; i += 256) {
        int val = __builtin_nontemporal_load(dn + i);
        if ((val & 128) == hsel) atomicAdd(&lh[val & 127], 1);
    }
    __syncthreads();
    if (tid < 128) {
        int node = b2 * 128 + tid;
        if (node < N) deg8[node] = (unsigned char)min(lh[tid], 255);
    }
    bf16x8 Bf[4][2];
#pragma unroll
    for (int t = 0; t < 4; ++t)
#pragma unroll
        for (int s = 0; s < 2; ++s)
            Bf[t][s] = *(const bf16x8*)(WT + (t * 16 + m) * 64 + s * 32 + quad * 8);
#pragma unroll
    for (int s = 0; s < 2; ++s) {
        int mt = b2 * 8 + s * 4 + wv;
        if (mt >= NT) continue;
        int row0 = mt * 16;
        bf16x8 A0, A1;
        A0[0] = (short)f2bf(xa[s][0][0]); A0[1] = (short)f2bf(xa[s][0][1]);
        A0[2] = (short)f2bf(xa[s][0][2]); A0[3] = (short)f2bf(xa[s][0][3]);
        A0[4] = (short)f2bf(xa[s][1][0]); A0[5] = (short)f2bf(xa[s][1][1]);
        A0[6] = (short)f2bf(xa[s][1][2]); A0[7] = (short)f2bf(xa[s][1][3]);
        A1[0] = (short)f2bf(xa[s][2][0]); A1[1] = (short)f2bf(xa[s][2][1]);
        A1[2] = (short)f2bf(xa[s][2][2]); A1[3] = (short)f2bf(xa[s][2][3]);
        A1[4] = (short)f2bf(xa[s][3][0]); A1[5] = (short)f2bf(xa[s][3][1]);
        A1[6] = (short)f2bf(xa[s][3][2]); A1[7] = (short)f2bf(xa[s][3][3]);
        f32x4 acc[4];
#pragma unroll
        for (int t = 0; t < 4; ++t) {
            acc[t] = (f32x4){0.f, 0.f, 0.f, 0.f};
            acc[t] = __builtin_amdgcn_mfma_f32_16x16x32_bf16(Bf[t][0], A0, acc[t], 0, 0, 0);
            acc[t] = __builtin_amdgcn_mfma_f32_16x16x32_bf16(Bf[t][1], A1, acc[t], 0, 0, 0);
        }
        float dsc = rsqrtf((float)(lh[(row0 + m) & 127] + 1));
        unsigned short* op = xw_h + (size_t)(row0 + m) * 64 + quad * 4;
#pragma unroll
        for (int t = 0; t < 4; ++t) {
            __half2 h0, h1;
            h0.x = __float2half(acc[t][0] * dsc); h0.y = __float2half(acc[t][1] * dsc);
            h1.x = __float2half(acc[t][2] * dsc); h1.y = __float2half(acc[t][3] * dsc);
            uint2 u; u.x = *(unsigned*)&h0; u.y = *(unsigned*)&h1;
            *(uint2*)(op + t * 16) = u;
        }
    }
}

// ---- 3. uniform-node gather, full buckets, 1024 thr, uint4 engine ----------
__global__ __launch_bounds__(1024, 8)
void k_gather(const int* __restrict__ dense, const int* __restrict__ gcur,
              const unsigned char* __restrict__ deg8,
              const uint4* __restrict__ xwh4, const float* __restrict__ bias,
              float* __restrict__ out, int N) {
    __shared__ int lh[BW], stt[BW], cur[BW];
    __shared__ int wsum[4];
    __shared__ __align__(16) int srtL[CAPL];
    int b = blockIdx.x, tid = threadIdx.x, lane = tid & 63;
    // per-node counts from deg8, padded-x16 exclusive scan (waves 0-3)
    int v = 0, vp = 0, inc = 0;
    if (tid < BW) {
        int node = b * BW + tid;
        v = (node < N) ? (int)deg8[node] : 0;
        lh[tid] = v;
        vp = (v + 15) & ~15; inc = vp;
#pragma unroll
        for (int o = 1; o < 64; o <<= 1) {
            int u = __shfl_up(inc, o);
            if (lane >= o) inc += u;
        }
        if (lane == 63) wsum[tid >> 6] = inc;
    }
    __syncthreads();
    if (tid < BW) {
        int wv4 = tid >> 6, woff = 0;
#pragma unroll
        for (int w = 0; w < 4; ++w) woff += (w < wv4) ? wsum[w] : 0;
        int st = woff + inc - vp;
        stt[tid] = st;
        cur[tid] = st;
    }
    __syncthreads();
    // rank-scatter from contiguous dense (single full read, no filter)
    int tot = min(gcur[b * GSTRIDE], CAPB);
    const int* dn = dense + (size_t)b * CAPB;
    for (int i = tid; i < tot; i += 1024) {
        int val = __builtin_nontemporal_load(dn + i);
        int pos = atomicAdd(&cur[val & 255], 1);
        if (pos < CAPL) srtL[pos] = val >> 8;
    }
    __syncthreads();
    {   // pad each segment to x16 with dummy row N (4 threads per node)
        int nn = tid >> 2, j = tid & 3;
        int vv = lh[nn];
        int e0p = stt[nn] + vv + j;
        int ep = min(stt[nn] + ((vv + 15) & ~15), CAPL);
        for (int e = e0p; e < ep; e += 4) srtL[e] = N;
    }
    __syncthreads();
    int q = lane >> 3;         // edge slot 0..7
    int l = lane & 7;          // dim chunk: uint4 = halves 8l..8l+7
    int wv = tid >> 6;         // 16 waves, 16 nodes each
    const float4 b0 = ((const float4*)bias)[2 * l];
    const float4 b1 = ((const float4*)bias)[2 * l + 1];
#define ADDV16(u)                                                     \
    {                                                                 \
        __half2 p0 = *(__half2*)&(u).x, p1 = *(__half2*)&(u).y;       \
        __half2 p2 = *(__half2*)&(u).z, p3 = *(__half2*)&(u).w;       \
        float2 f0 = __half22float2(p0), f1 = __half22float2(p1);      \
        float2 f2 = __half22float2(p2), f3 = __half22float2(p3);      \
        accA.x += f0.x; accA.y += f0.y; accA.z += f1.x; accA.w += f1.y;\
        accB.x += f2.x; accB.y += f2.y; accB.z += f3.x; accB.w += f3.y;\
    }
    for (int nn = wv * 16; nn < wv * 16 + 16; ++nn) {
        int node = b * BW + nn;
        if (node >= N) break;
        int k = lh[nn], s0 = stt[nn];
        int kp = (k + 15) & ~15;
        if (s0 + kp > CAPL) kp = (CAPL > s0) ? ((CAPL - s0) & ~15) : 0;
        float4 accA = make_float4(0.f, 0.f, 0.f, 0.f);
        float4 accB = make_float4(0.f, 0.f, 0.f, 0.f);
        if (q == 0) { uint4 hs = xwh4[(size_t)node * 8 + l]; ADDV16(hs); } // self
        int rounds = kp >> 4;
        if (rounds > 0) {      // 2-stage pipeline: 4 uint4 loads in flight
            int i0 = s0 + q;
            int r0 = srtL[i0], r1 = srtL[i0 + 8];
            uint4 va = xwh4[(size_t)r0 * 8 + l];
            uint4 vb = xwh4[(size_t)r1 * 8 + l];
            for (int r = 1; r < rounds; ++r) {
                i0 += 16;
                int n0 = srtL[i0], n1 = srtL[i0 + 8];
                uint4 wa = xwh4[(size_t)n0 * 8 + l];
                uint4 wb = xwh4[(size_t)n1 * 8 + l];
                ADDV16(va); ADDV16(vb);
                va = wa; vb = wb;
            }
            ADDV16(va); ADDV16(vb);
        }
        // reduce across the 8 edge slots (q): xor 8, 16, 32
#pragma unroll
        for (int mm = 8; mm < 64; mm <<= 1) {
            accA.x += __shfl_xor(accA.x, mm); accA.y += __shfl_xor(accA.y, mm);
            accA.z += __shfl_xor(accA.z, mm); accA.w += __shfl_xor(accA.w, mm);
            accB.x += __shfl_xor(accB.x, mm); accB.y += __shfl_xor(accB.y, mm);
            accB.z += __shfl_xor(accB.z, mm); accB.w += __shfl_xor(accB.w, mm);
        }
        if (q == 0) {
            float dn2 = rsqrtf((float)(k + 1));
            f32x4 o1, o2;
            o1[0] = fmaxf(fmaf(dn2, accA.x, b0.x), 0.f);
            o1[1] = fmaxf(fmaf(dn2, accA.y, b0.y), 0.f);
            o1[2] = fmaxf(fmaf(dn2, accA.z, b0.z), 0.f);
            o1[3] = fmaxf(fmaf(dn2, accA.w, b0.w), 0.f);
            o2[0] = fmaxf(fmaf(dn2, accB.x, b1.x), 0.f);
            o2[1] = fmaxf(fmaf(dn2, accB.y, b1.y), 0.f);
            o2[2] = fmaxf(fmaf(dn2, accB.z, b1.z), 0.f);
            o2[3] = fmaxf(fmaf(dn2, accB.w, b1.w), 0.f);
            float* op = out + (size_t)node * 64 + l * 8;
            __builtin_nontemporal_store(o1, (f32x4*)op);
            __builtin_nontemporal_store(o2, (f32x4*)(op + 4));
        }
    }
#undef ADDV16
}

extern "C" void kernel_launch(void* const* d_in, const int* in_sizes, int n_in,
                              void* d_out, int out_size, void* d_ws, size_t ws_size,
                              hipStream_t stream) {
    const float* x    = (const float*)d_in[0];
    const int*   ei   = (const int*)d_in[1];   // int32 (JAX demotes int64)
    const float* W    = (const float*)d_in[2];
    const float* bias = (const float*)d_in[3];
    float* out = (float*)d_out;

    const int N = in_sizes[0] / D;
    const int E = in_sizes[1] / 2;
    const int* row = ei;       // edge_index[0] = sources
    const int* col = ei + E;   // edge_index[1] = destinations

    const int NBUCK = (N + BW - 1) / BW;       // 391
    const int NB1   = (E + EPB - 1) / EPB;     // 391
    const int NT    = (N + 15) / 16;           // 6250 M-tiles
    const int NH    = 2 * NBUCK;               // 782 half-buckets (gemm)

    char* ws = (char*)d_ws;
    size_t o = 0;
    unsigned short* xw_h = (unsigned short*)(ws + o);
    o += (size_t)(N + 1) * D * sizeof(unsigned short);             // 12.8 MB
    int* dense = (int*)(ws + o); o += (size_t)NBUCK * CAPB * sizeof(int); // 7.5 MB
    int* gcur  = (int*)(ws + o); o += (size_t)NBUCK * GSTRIDE * sizeof(int); // 25 KB
    unsigned char* deg8 = (unsigned char*)(ws + o); o += (size_t)N;
    o = (o + 15) & ~(size_t)15;
    unsigned short* WT = (unsigned short*)(ws + o); o += 4096 * sizeof(unsigned short);

    hipMemsetAsync(gcur, 0, (size_t)NBUCK * GSTRIDE * sizeof(int), stream);
    k_part<<<NB1, PART_T, 0, stream>>>(row, col, gcur, dense, WT, W, xw_h, E, NBUCK, N);
    k_gemm<<<NH, 256, 0, stream>>>(x, WT, dense, gcur, deg8, xw_h, N, NT);
    k_gather<<<NBUCK, 1024, 0, stream>>>(dense, gcur, deg8, (const uint4*)xw_h,
                                         bias, out, N);
}